// Round 3
// baseline (92.184 us; speedup 1.0000x reference)
//
#include <hip/hip_runtime.h>

// RippleNetPlus fused — 1 block (256 thr) per batch element. DIM=32, HOP=2, MEM=32.
//
// Round 3 structure:
//  init: stage W1 as float4 quad {a,b,c,d}[i][o] in LDS (XOR-swizzled col o^i,
//        coalesced global reads), prefetch t-rows (both hops) + GRU biases,
//        compute Rh(hop0) into s_rh[0] (8 groups x 4 mem, coalesced b128 +
//        packed butterfly, contiguous b128 LDS write).
//  per hop: [waves0-1: hidden+score for 8 mem/group | waves2-3 (hop0): Rh(hop1)
//        into s_rh[1]] -> bar -> softmax redundantly on all lanes + weighted-t
//        partials -> bar -> GRU gates distributed over 256 thr w/ coalesced
//        b128 weight loads -> bar -> GRU update (32 lanes) -> bar.
//  epilogue: distributed ans matvec + 32-lane final dot.

#define NHOP 2

__device__ __forceinline__ float sigmoid_f(float x){ return 1.0f/(1.0f+__expf(-x)); }
__device__ __forceinline__ float tanh_f(float x){
  float e = __expf(2.0f*x);
  return 1.0f - 2.0f/(e + 1.0f);
}

__global__ __launch_bounds__(256) void ripple_fused(
    const int* __restrict__ h_i, const int* __restrict__ R_i, const int* __restrict__ t_i,
    const int* __restrict__ v_i,
    const float* __restrict__ entity_emb, const float* __restrict__ relation_emb,
    const float* __restrict__ agg_w1, const float* __restrict__ agg_b1,
    const float* __restrict__ agg_w2, const float* __restrict__ agg_b2,
    const float* __restrict__ gru_w_ih, const float* __restrict__ gru_w_hh,
    const float* __restrict__ gru_b_ih, const float* __restrict__ gru_b_hh,
    const float* __restrict__ ans_w, const float* __restrict__ ans_b,
    float* __restrict__ out)
{
  __shared__ __align__(16) float s_w4 [32*32*4];   // 16KB quad {w1a,w1b,w1c,w1d}[i][o^i]
  __shared__ __align__(16) float s_rh [2][8*32*4]; // 8KB  [buf][g][j]{m0..m3}
  __shared__ __align__(16) float s_vsM[32*2];      // [i]{vs,M}
  __shared__ __align__(16) float s_Z  [32];
  __shared__ __align__(16) float s_opart[8*32];
  __shared__ __align__(16) float s_M  [32];
  __shared__ __align__(16) float s_gig[192];       // gi[0:96], gh[96:192]

  const int b   = blockIdx.x;
  const int tid = threadIdx.x;
  const int g   = tid >> 5;   // group 0..7
  const int o   = tid & 31;
  const int c   = o & 7;
  const int r_  = o >> 3;
  const bool bb4 = (c & 4) != 0;
  const bool bb2 = (c & 2) != 0;
  const bool bb1 = (c & 1) != 0;

  const int ibase0 = (b*NHOP + 0)*32;
  const int ibase1 = (b*NHOP + 1)*32;

  // Rh for 4 memories (mbase..mbase+3) -> buf row `row` (contiguous b128 write)
  auto compute_rh = [&](int row, int mbase, float* buf, int ibase){
    float rh4[4];
    #pragma unroll
    for (int ml = 0; ml < 4; ++ml){
      int m    = mbase + ml;
      int ridx = R_i[ibase + m];
      int hidx = h_i[ibase + m];
      const float* Rbase = relation_emb + (size_t)ridx*1024;
      float4 hv = *(const float4*)(entity_emb + (size_t)hidx*32 + c*4);
      float p[8];
      #pragma unroll
      for (int q = 0; q < 8; ++q){
        float4 rv = *(const float4*)(Rbase + q*128 + o*4);
        p[q] = rv.x*hv.x + rv.y*hv.y + rv.z*hv.z + rv.w*hv.w;
      }
      #pragma unroll
      for (int k = 0; k < 4; ++k){
        float send = bb4 ? p[k] : p[k+4];
        float t = __shfl_xor(send, 4);
        p[k] = (bb4 ? p[k+4] : p[k]) + t;
      }
      #pragma unroll
      for (int k = 0; k < 2; ++k){
        float send = bb2 ? p[k] : p[k+2];
        float t = __shfl_xor(send, 2);
        p[k] = (bb2 ? p[k+2] : p[k]) + t;
      }
      {
        float send = bb1 ? p[0] : p[1];
        float t = __shfl_xor(send, 1);
        p[0] = (bb1 ? p[1] : p[0]) + t;
      }
      rh4[ml] = p[0];
    }
    int j = c*4 + r_;   // bijective lane->row
    *(float4*)&buf[(row*32 + j)*4] = make_float4(rh4[0],rh4[1],rh4[2],rh4[3]);
  };

  // ---- init: stage W quad (coalesced reads, swizzled conflict-free write) ----
  #pragma unroll
  for (int k = 0; k < 4; ++k){
    int ii = o;
    int oo = (tid >> 5) + 8*k;
    float wa = agg_w1[oo*128       + ii];
    float wb = agg_w1[oo*128 + 32  + ii];
    float wc = agg_w1[oo*128 + 64  + ii];
    float wd = agg_w1[oo*128 + 96  + ii];
    *(float4*)&s_w4[(ii*32 + (oo ^ ii))*4] = make_float4(wa,wb,wc,wd);
  }

  float Mreg = 0.f;
  if (tid < 32){
    float v = entity_emb[(size_t)v_i[b]*32 + o];
    s_vsM[o*2+0] = v; s_vsM[o*2+1] = v; s_M[o] = v;
    Mreg = v;
  }

  // t-row prefetch for both hops (group g owns memories 4g..4g+3)
  float tv0[4], tv1[4];
  #pragma unroll
  for (int ml = 0; ml < 4; ++ml){
    tv0[ml] = entity_emb[(size_t)t_i[ibase0 + g*4 + ml]*32 + o];
    tv1[ml] = entity_emb[(size_t)t_i[ibase1 + g*4 + ml]*32 + o];
  }

  // GRU bias prefetch (consumed by lanes 0..31 in update phase)
  float bi0[3], bh0[3], bi1[3], bh1[3];
  if (tid < 32){
    #pragma unroll
    for (int k = 0; k < 3; ++k){
      bi0[k] = gru_b_ih[      32*k + o];
      bh0[k] = gru_b_hh[      32*k + o];
      bi1[k] = gru_b_ih[96 +  32*k + o];
      bh1[k] = gru_b_hh[96 +  32*k + o];
    }
  }

  const float b1v = agg_b1[o];
  const float w2v = agg_w2[o];

  compute_rh(g, g*4, s_rh[0], ibase0);   // A(0), all 8 groups
  __syncthreads();

  #pragma unroll
  for (int hop = 0; hop < NHOP; ++hop){
    const float* bufC = s_rh[hop];

    // ---- phase B (waves 0-1) : hidden + scores, 8 memories per half-wave ----
    if (tid < 128){
      const int gb = tid >> 5;   // 0..3, memories 8gb..8gb+7
      const float4* w4p   = (const float4*)s_w4;
      const float4* rlo_p = (const float4*)&bufC[((2*gb  )*32)*4];
      const float4* rhi_p = (const float4*)&bufC[((2*gb+1)*32)*4];
      float acc[8] = {0,0,0,0,0,0,0,0};
      #pragma unroll 8
      for (int i = 0; i < 32; ++i){
        float4 wq = w4p[i*32 + (o ^ i)];
        float2 vm = *(const float2*)&s_vsM[i*2];
        float  cp = vm.x*wq.x + vm.y*wq.y;
        float4 rlo = rlo_p[i];
        float4 rhi = rhi_p[i];
        acc[0] += rlo.x*cp + fabsf(rlo.x-vm.x)*wq.z + fabsf(rlo.x-vm.y)*wq.w;
        acc[1] += rlo.y*cp + fabsf(rlo.y-vm.x)*wq.z + fabsf(rlo.y-vm.y)*wq.w;
        acc[2] += rlo.z*cp + fabsf(rlo.z-vm.x)*wq.z + fabsf(rlo.z-vm.y)*wq.w;
        acc[3] += rlo.w*cp + fabsf(rlo.w-vm.x)*wq.z + fabsf(rlo.w-vm.y)*wq.w;
        acc[4] += rhi.x*cp + fabsf(rhi.x-vm.x)*wq.z + fabsf(rhi.x-vm.y)*wq.w;
        acc[5] += rhi.y*cp + fabsf(rhi.y-vm.x)*wq.z + fabsf(rhi.y-vm.y)*wq.w;
        acc[6] += rhi.z*cp + fabsf(rhi.z-vm.x)*wq.z + fabsf(rhi.z-vm.y)*wq.w;
        acc[7] += rhi.w*cp + fabsf(rhi.w-vm.x)*wq.z + fabsf(rhi.w-vm.y)*wq.w;
      }
      float v8[8];
      #pragma unroll
      for (int k = 0; k < 8; ++k) v8[k] = tanh_f(acc[k] + b1v) * w2v;
      // packed butterfly: 8 values over 32 lanes (9 shfl)
      const bool t4 = (o & 16) != 0;
      #pragma unroll
      for (int k = 0; k < 4; ++k){
        float send = t4 ? v8[k] : v8[k+4];
        float t = __shfl_xor(send, 16);
        v8[k] = (t4 ? v8[k+4] : v8[k]) + t;
      }
      const bool t3 = (o & 8) != 0;
      #pragma unroll
      for (int k = 0; k < 2; ++k){
        float send = t3 ? v8[k] : v8[k+2];
        float t = __shfl_xor(send, 8);
        v8[k] = (t3 ? v8[k+2] : v8[k]) + t;
      }
      const bool t2 = (o & 4) != 0;
      {
        float send = t2 ? v8[0] : v8[1];
        float t = __shfl_xor(send, 4);
        v8[0] = (t2 ? v8[1] : v8[0]) + t;
      }
      v8[0] += __shfl_xor(v8[0], 2);
      v8[0] += __shfl_xor(v8[0], 1);
      if ((o & 3) == 0){
        int ml = ((o>>4)&1)*4 + ((o>>3)&1)*2 + ((o>>2)&1);
        s_Z[gb*8 + ml] = v8[0];
      }
    } else if (hop == 0){
      // ---- waves 2-3: prefetch-compute Rh(hop1) into buffer 1 ----
      const int ga = (tid >> 5) - 4;   // 0..3
      compute_rh(2*ga,   8*ga,   s_rh[1], ibase1);
      compute_rh(2*ga+1, 8*ga+4, s_rh[1], ibase1);
    }
    __syncthreads();

    // ---- phase C: softmax redundantly on all lanes; weighted-t partials ----
    {
      float z  = s_Z[o];
      float mx = z;
      #pragma unroll
      for (int s = 16; s > 0; s >>= 1) mx = fmaxf(mx, __shfl_xor(mx, s));
      float e  = __expf(z - mx);
      float sm = e;
      #pragma unroll
      for (int s = 16; s > 0; s >>= 1) sm += __shfl_xor(sm, s);
      float gval = e / sm;   // lane o holds gate for memory o
      float po = 0.f;
      #pragma unroll
      for (int ml = 0; ml < 4; ++ml){
        float gm = __shfl(gval, g*4 + ml);
        po += gm * (hop == 0 ? tv0[ml] : tv1[ml]);
      }
      s_opart[g*32 + o] = po;
    }
    __syncthreads();

    // ---- phase D: GRU gates, distributed, coalesced b128 weight loads ----
    {
      const int cc = (tid & 7) * 4;
      const int rr = tid >> 3;          // 0..31
      float4 o4 = make_float4(0,0,0,0);
      #pragma unroll
      for (int gg = 0; gg < 8; ++gg){
        float4 t = *(const float4*)&s_opart[gg*32 + cc];
        o4.x += t.x; o4.y += t.y; o4.z += t.z; o4.w += t.w;
      }
      float4 m4 = *(const float4*)&s_M[cc];
      #pragma unroll
      for (int k = 0; k < 3; ++k){
        int row = k*32 + rr;
        float4 wi = *(const float4*)(gru_w_ih + ((size_t)hop*96 + row)*32 + cc);
        float4 wh = *(const float4*)(gru_w_hh + ((size_t)hop*96 + row)*32 + cc);
        float ai = wi.x*o4.x + wi.y*o4.y + wi.z*o4.z + wi.w*o4.w;
        float ah = wh.x*m4.x + wh.y*m4.y + wh.z*m4.z + wh.w*m4.w;
        ai += __shfl_xor(ai,1); ai += __shfl_xor(ai,2); ai += __shfl_xor(ai,4);
        ah += __shfl_xor(ah,1); ah += __shfl_xor(ah,2); ah += __shfl_xor(ah,4);
        if ((tid & 7) == 0){
          s_gig[row]      = ai;
          s_gig[96 + row] = ah;
        }
      }
    }
    __syncthreads();

    // ---- phase E: GRU state update (lanes 0..31) ----
    if (tid < 32){
      float ir = s_gig[o]       + (hop==0 ? bi0[0] : bi1[0]);
      float iz = s_gig[32 + o]  + (hop==0 ? bi0[1] : bi1[1]);
      float in_= s_gig[64 + o]  + (hop==0 ? bi0[2] : bi1[2]);
      float hr = s_gig[96 + o]  + (hop==0 ? bh0[0] : bh1[0]);
      float hz = s_gig[128 + o] + (hop==0 ? bh0[1] : bh1[1]);
      float hn = s_gig[160 + o] + (hop==0 ? bh0[2] : bh1[2]);
      float r  = sigmoid_f(ir + hr);
      float zz = sigmoid_f(iz + hz);
      float n  = tanh_f(in_ + r*hn);
      float Mn = (1.f - zz)*n + zz*Mreg;
      Mreg = Mn;
      s_M[o] = Mn;
      s_vsM[o*2+1] = Mn;
    }
    __syncthreads();
  }

  // ---- epilogue: Mw = sigmoid(M @ ans_w.T + ans_b); out = vs . Mw ----
  {
    const int cc = (tid & 7) * 4;
    const int rr = tid >> 3;
    float4 m4 = *(const float4*)&s_M[cc];
    float4 aw = *(const float4*)(ans_w + (size_t)rr*32 + cc);
    float a = aw.x*m4.x + aw.y*m4.y + aw.z*m4.z + aw.w*m4.w;
    a += __shfl_xor(a,1); a += __shfl_xor(a,2); a += __shfl_xor(a,4);
    if ((tid & 7) == 0) s_Z[rr] = sigmoid_f(a + ans_b[rr]);
  }
  __syncthreads();
  if (tid < 32){
    float val = s_vsM[o*2+0] * s_Z[o];
    #pragma unroll
    for (int s = 16; s > 0; s >>= 1) val += __shfl_xor(val, s);
    if (tid == 0) out[b] = val;
  }
}

extern "C" void kernel_launch(void* const* d_in, const int* in_sizes, int n_in,
                              void* d_out, int out_size, void* d_ws, size_t ws_size,
                              hipStream_t stream) {
  const int*   h_i          = (const int*)  d_in[0];
  const int*   R_i          = (const int*)  d_in[1];
  const int*   t_i          = (const int*)  d_in[2];
  const int*   v_i          = (const int*)  d_in[3];
  const float* entity_emb   = (const float*)d_in[4];
  const float* relation_emb = (const float*)d_in[5];
  const float* agg_w1       = (const float*)d_in[6];
  const float* agg_b1       = (const float*)d_in[7];
  const float* agg_w2       = (const float*)d_in[8];
  const float* agg_b2       = (const float*)d_in[9];   // dropped: constant shift, softmax-invariant
  const float* gru_w_ih     = (const float*)d_in[10];
  const float* gru_w_hh     = (const float*)d_in[11];
  const float* gru_b_ih     = (const float*)d_in[12];
  const float* gru_b_hh     = (const float*)d_in[13];
  const float* ans_w        = (const float*)d_in[14];
  const float* ans_b        = (const float*)d_in[15];
  (void)agg_b2;
  float* outp = (float*)d_out;

  const int batch = in_sizes[3];
  ripple_fused<<<batch, 256, 0, stream>>>(
      h_i, R_i, t_i, v_i, entity_emb, relation_emb,
      agg_w1, agg_b1, agg_w2, agg_b2,
      gru_w_ih, gru_w_hh, gru_b_ih, gru_b_hh,
      ans_w, ans_b, outp);
}

// Round 4
// 69.012 us; speedup vs baseline: 1.3358x; 1.3358x over previous
//
#include <hip/hip_runtime.h>

// RippleNetPlus fused — 1 block (256 thr) per batch element. DIM=32, HOP=2, MEM=32.
//
// Round 4: round-2 skeleton (8 blocks/CU) + register-free improvements.
//  - W1 staged once as bf16 quad {wa,wb,wc,wd}[i][o^i] in LDS (8 KB): no
//    per-hop C' build phase/barrier/gather; cp computed inline (2 FMA).
//  - all-lane softmax + distributed GRU gates/epilogue (no 32-thread phases,
//    5 barriers/hop instead of 7).
//  - packed 4-value score butterfly (6 shfl vs 20).
//  - __launch_bounds__(256,8) pins VGPR<=64 so 8 blocks/CU hold.

#define NHOP 2

__device__ __forceinline__ float sigmoid_f(float x){ return 1.0f/(1.0f+__expf(-x)); }
__device__ __forceinline__ float tanh_f(float x){
  float e = __expf(2.0f*x);
  return 1.0f - 2.0f/(e + 1.0f);
}
__device__ __forceinline__ unsigned bf16_rtne(float x){
  unsigned u = __float_as_uint(x);
  return (u + 0x7fffu + ((u >> 16) & 1u)) >> 16;
}

__global__ __launch_bounds__(256, 8) void ripple_fused(
    const int* __restrict__ h_i, const int* __restrict__ R_i, const int* __restrict__ t_i,
    const int* __restrict__ v_i,
    const float* __restrict__ entity_emb, const float* __restrict__ relation_emb,
    const float* __restrict__ agg_w1, const float* __restrict__ agg_b1,
    const float* __restrict__ agg_w2, const float* __restrict__ agg_b2,
    const float* __restrict__ gru_w_ih, const float* __restrict__ gru_w_hh,
    const float* __restrict__ gru_b_ih, const float* __restrict__ gru_b_hh,
    const float* __restrict__ ans_w, const float* __restrict__ ans_b,
    float* __restrict__ out)
{
  __shared__ __align__(16) uint2 s_wq[32*32];      // 8 KB bf16 quad, col o^i
  __shared__ __align__(16) float s_rh [8*32*4];    // 4 KB [g][i]{m0..m3}
  __shared__ __align__(16) float s_vsM[32*2];      // [i]{vs,M}
  __shared__ __align__(16) float s_Z  [32];
  __shared__ __align__(16) float s_opart[8*32];    // 1 KB
  __shared__ __align__(16) float s_M  [32];
  __shared__ __align__(16) float s_gig[192];       // gi[0:96], gh[96:192]

  const int b   = blockIdx.x;
  const int tid = threadIdx.x;
  const int g   = tid >> 5;   // group 0..7
  const int o   = tid & 31;
  const int c   = o & 7;
  const int r_  = o >> 3;
  const bool bb4 = (c & 4) != 0;
  const bool bb2 = (c & 2) != 0;
  const bool bb1 = (c & 1) != 0;

  // ---- init: W quad, coalesced global reads -> bf16 RTNE -> swizzled LDS ----
  #pragma unroll
  for (int k = 0; k < 4; ++k){
    int ii = o;
    int oo = g + 8*k;
    float wa = agg_w1[oo*128       + ii];
    float wb = agg_w1[oo*128 + 32  + ii];
    float wc = agg_w1[oo*128 + 64  + ii];
    float wd = agg_w1[oo*128 + 96  + ii];
    s_wq[ii*32 + (oo ^ ii)] = make_uint2(bf16_rtne(wa) | (bf16_rtne(wb) << 16),
                                         bf16_rtne(wc) | (bf16_rtne(wd) << 16));
  }
  float Mreg = 0.f;
  if (tid < 32){
    float v = entity_emb[(size_t)v_i[b]*32 + o];
    s_vsM[o*2+0] = v; s_vsM[o*2+1] = v; s_M[o] = v;
    Mreg = v;
  }
  __syncthreads();

  const float b1v = agg_b1[o];
  const float w2v = agg_w2[o];

  for (int hop = 0; hop < NHOP; ++hop){
    const int ibase = (b*NHOP + hop)*32;

    // ---- t-row prefetch (latency hides under phase A/B) ----
    float tv[4];
    #pragma unroll
    for (int ml = 0; ml < 4; ++ml)
      tv[ml] = entity_emb[(size_t)t_i[ibase + g*4 + ml]*32 + o];

    // ---- phase A: Rh for this group's 4 memories (coalesced + butterfly) ----
    {
      float rh4[4];
      #pragma unroll
      for (int ml = 0; ml < 4; ++ml){
        int m    = g*4 + ml;
        int ridx = R_i[ibase + m];
        int hidx = h_i[ibase + m];
        const float* Rbase = relation_emb + (size_t)ridx*1024;
        float4 hv = *(const float4*)(entity_emb + (size_t)hidx*32 + c*4);
        float p[8];
        #pragma unroll
        for (int q = 0; q < 8; ++q){
          float4 rv = *(const float4*)(Rbase + q*128 + o*4);
          p[q] = rv.x*hv.x + rv.y*hv.y + rv.z*hv.z + rv.w*hv.w;
        }
        #pragma unroll
        for (int k = 0; k < 4; ++k){
          float send = bb4 ? p[k] : p[k+4];
          float t = __shfl_xor(send, 4);
          p[k] = (bb4 ? p[k+4] : p[k]) + t;
        }
        #pragma unroll
        for (int k = 0; k < 2; ++k){
          float send = bb2 ? p[k] : p[k+2];
          float t = __shfl_xor(send, 2);
          p[k] = (bb2 ? p[k+2] : p[k]) + t;
        }
        {
          float send = bb1 ? p[0] : p[1];
          float t = __shfl_xor(send, 1);
          p[0] = (bb1 ? p[1] : p[0]) + t;
        }
        rh4[ml] = p[0];
      }
      int j = c*4 + r_;   // bijective lane->row
      *(float4*)&s_rh[(g*32 + j)*4] = make_float4(rh4[0],rh4[1],rh4[2],rh4[3]);
    }
    __syncthreads();

    // ---- phase B: hidden + score, 4 memories per group ----
    {
      const float4* rh_p = (const float4*)&s_rh[(g*32)*4];
      float a0=0.f, a1=0.f, a2=0.f, a3=0.f;
      #pragma unroll 8
      for (int i = 0; i < 32; ++i){
        uint2 wd2 = s_wq[i*32 + (o ^ i)];
        float wa = __uint_as_float(wd2.x << 16);
        float wb = __uint_as_float(wd2.x & 0xffff0000u);
        float wc = __uint_as_float(wd2.y << 16);
        float wd = __uint_as_float(wd2.y & 0xffff0000u);
        float2 vm = *(const float2*)&s_vsM[i*2];
        float  cp = vm.x*wa + vm.y*wb;
        float4 rh = rh_p[i];
        a0 += rh.x*cp + fabsf(rh.x-vm.x)*wc + fabsf(rh.x-vm.y)*wd;
        a1 += rh.y*cp + fabsf(rh.y-vm.x)*wc + fabsf(rh.y-vm.y)*wd;
        a2 += rh.z*cp + fabsf(rh.z-vm.x)*wc + fabsf(rh.z-vm.y)*wd;
        a3 += rh.w*cp + fabsf(rh.w-vm.x)*wc + fabsf(rh.w-vm.y)*wd;
      }
      float v4[4];
      v4[0] = tanh_f(a0 + b1v) * w2v;
      v4[1] = tanh_f(a1 + b1v) * w2v;
      v4[2] = tanh_f(a2 + b1v) * w2v;
      v4[3] = tanh_f(a3 + b1v) * w2v;
      // packed butterfly: 4 values over 32 lanes (6 shfl)
      const bool t4 = (o & 16) != 0;
      #pragma unroll
      for (int k = 0; k < 2; ++k){
        float send = t4 ? v4[k] : v4[k+2];
        float t = __shfl_xor(send, 16);
        v4[k] = (t4 ? v4[k+2] : v4[k]) + t;
      }
      const bool t3 = (o & 8) != 0;
      {
        float send = t3 ? v4[0] : v4[1];
        float t = __shfl_xor(send, 8);
        v4[0] = (t3 ? v4[1] : v4[0]) + t;
      }
      v4[0] += __shfl_xor(v4[0], 4);
      v4[0] += __shfl_xor(v4[0], 2);
      v4[0] += __shfl_xor(v4[0], 1);
      if ((o & 7) == 0){
        int ml = ((o >> 4) & 1)*2 + ((o >> 3) & 1);
        s_Z[g*4 + ml] = v4[0];
      }
    }
    __syncthreads();

    // ---- phase C: softmax on all lanes; weighted-t partials ----
    {
      float z  = s_Z[o];
      float mx = z;
      #pragma unroll
      for (int s = 16; s > 0; s >>= 1) mx = fmaxf(mx, __shfl_xor(mx, s));
      float e  = __expf(z - mx);
      float sm = e;
      #pragma unroll
      for (int s = 16; s > 0; s >>= 1) sm += __shfl_xor(sm, s);
      float gval = e / sm;   // lane o holds gate for memory o
      float po = 0.f;
      #pragma unroll
      for (int ml = 0; ml < 4; ++ml)
        po += __shfl(gval, g*4 + ml) * tv[ml];
      s_opart[g*32 + o] = po;
    }
    __syncthreads();

    // ---- phase D: GRU gates, distributed, coalesced b128 weight loads ----
    {
      const int cc = (tid & 7) * 4;
      const int rr = tid >> 3;          // 0..31
      float4 o4 = make_float4(0,0,0,0);
      #pragma unroll
      for (int gg = 0; gg < 8; ++gg){
        float4 t = *(const float4*)&s_opart[gg*32 + cc];
        o4.x += t.x; o4.y += t.y; o4.z += t.z; o4.w += t.w;
      }
      float4 m4 = *(const float4*)&s_M[cc];
      #pragma unroll
      for (int k = 0; k < 3; ++k){
        int row = k*32 + rr;
        float4 wi = *(const float4*)(gru_w_ih + ((size_t)hop*96 + row)*32 + cc);
        float4 wh = *(const float4*)(gru_w_hh + ((size_t)hop*96 + row)*32 + cc);
        float ai = wi.x*o4.x + wi.y*o4.y + wi.z*o4.z + wi.w*o4.w;
        float ah = wh.x*m4.x + wh.y*m4.y + wh.z*m4.z + wh.w*m4.w;
        ai += __shfl_xor(ai,1); ai += __shfl_xor(ai,2); ai += __shfl_xor(ai,4);
        ah += __shfl_xor(ah,1); ah += __shfl_xor(ah,2); ah += __shfl_xor(ah,4);
        if ((tid & 7) == 0){
          s_gig[row]      = ai;
          s_gig[96 + row] = ah;
        }
      }
    }
    __syncthreads();

    // ---- phase E: GRU state update (lanes 0..31), biases from global ----
    if (tid < 32){
      const float* bih = gru_b_ih + hop*96;
      const float* bhh = gru_b_hh + hop*96;
      float ir = s_gig[o]       + bih[o];
      float iz = s_gig[32 + o]  + bih[32 + o];
      float in_= s_gig[64 + o]  + bih[64 + o];
      float hr = s_gig[96 + o]  + bhh[o];
      float hz = s_gig[128 + o] + bhh[32 + o];
      float hn = s_gig[160 + o] + bhh[64 + o];
      float r  = sigmoid_f(ir + hr);
      float zz = sigmoid_f(iz + hz);
      float n  = tanh_f(in_ + r*hn);
      float Mn = (1.f - zz)*n + zz*Mreg;
      Mreg = Mn;
      s_M[o] = Mn;
      s_vsM[o*2+1] = Mn;
    }
    __syncthreads();
  }

  // ---- epilogue: Mw = sigmoid(M @ ans_w.T + ans_b); out = vs . Mw ----
  {
    const int cc = (tid & 7) * 4;
    const int rr = tid >> 3;
    float4 m4 = *(const float4*)&s_M[cc];
    float4 aw = *(const float4*)(ans_w + (size_t)rr*32 + cc);
    float a = aw.x*m4.x + aw.y*m4.y + aw.z*m4.z + aw.w*m4.w;
    a += __shfl_xor(a,1); a += __shfl_xor(a,2); a += __shfl_xor(a,4);
    if ((tid & 7) == 0) s_Z[rr] = sigmoid_f(a + ans_b[rr]);
  }
  __syncthreads();
  if (tid < 32){
    float val = s_vsM[o*2+0] * s_Z[o];
    #pragma unroll
    for (int s = 16; s > 0; s >>= 1) val += __shfl_xor(val, s);
    if (tid == 0) out[b] = val;
  }
}

extern "C" void kernel_launch(void* const* d_in, const int* in_sizes, int n_in,
                              void* d_out, int out_size, void* d_ws, size_t ws_size,
                              hipStream_t stream) {
  const int*   h_i          = (const int*)  d_in[0];
  const int*   R_i          = (const int*)  d_in[1];
  const int*   t_i          = (const int*)  d_in[2];
  const int*   v_i          = (const int*)  d_in[3];
  const float* entity_emb   = (const float*)d_in[4];
  const float* relation_emb = (const float*)d_in[5];
  const float* agg_w1       = (const float*)d_in[6];
  const float* agg_b1       = (const float*)d_in[7];
  const float* agg_w2       = (const float*)d_in[8];
  const float* agg_b2       = (const float*)d_in[9];   // softmax-invariant, dropped
  const float* gru_w_ih     = (const float*)d_in[10];
  const float* gru_w_hh     = (const float*)d_in[11];
  const float* gru_b_ih     = (const float*)d_in[12];
  const float* gru_b_hh     = (const float*)d_in[13];
  const float* ans_w        = (const float*)d_in[14];
  const float* ans_b        = (const float*)d_in[15];
  (void)agg_b2;
  float* outp = (float*)d_out;

  const int batch = in_sizes[3];
  ripple_fused<<<batch, 256, 0, stream>>>(
      h_i, R_i, t_i, v_i, entity_emb, relation_emb,
      agg_w1, agg_b1, agg_w2, agg_b2,
      gru_w_ih, gru_w_hh, gru_b_ih, gru_b_hh,
      ans_w, ans_b, outp);
}